// Round 1
// baseline (392.900 us; speedup 1.0000x reference)
//
#include <hip/hip_runtime.h>
#include <math.h>

// NetVLAD fused fp32 baseline.
// Sizes fixed by the problem: N=64, C=128, H=W=64 (P=4096), K=64.
#define NN 64
#define CC 128
#define KK 64
#define PPIX 4096
#define BSPLIT 8            // blocks per image
#define PB (PPIX / BSPLIT)  // 512 pixels per block
#define TT 32               // pixel chunk staged in LDS
#define XS 132              // x_lds row stride (pad 128->132, keeps float4 align)
#define WSR 132             // w_lds row stride
#define AS 68               // a_lds row stride (pad 64->68, keeps float4 align)

__global__ __launch_bounds__(256) void netvlad_fused(
    const float* __restrict__ x, const float* __restrict__ conv_w,
    const float* __restrict__ conv_b, float* __restrict__ vlad_part,
    float* __restrict__ asum_part) {
  __shared__ __align__(16) float w_lds[KK * WSR];   // 33792 B
  __shared__ __align__(16) float x_lds[TT * XS];    // 16896 B  [p][c]
  __shared__ __align__(16) float a_lds[TT * AS];    //  8704 B  [p][k]
  __shared__ float b_lds[KK];

  const int t = threadIdx.x;
  const int n = blockIdx.x / BSPLIT;
  const int blk = blockIdx.x % BSPLIT;
  const int p_base = blk * PB;

  // ---- stage conv_w (K x C) into padded LDS rows ----
  for (int i = t; i < KK * CC / 4; i += 256) {
    int k = i >> 5;              // 32 float4 per row
    int c4 = (i & 31) << 2;
    float4 v = ((const float4*)conv_w)[i];
    *(float4*)&w_lds[k * WSR + c4] = v;
  }
  if (t < KK) b_lds[t] = conv_b[t];

  // thread tiling (same k-mapping for logits and vlad phases)
  const int tp = t & 15;           // logits: p = tp, tp+16
  const int k0 = (t >> 4) << 2;    // 4 consecutive k per thread
  const int tc = t & 15;           // vlad:   c0 = tc*8
  const int c0 = tc << 3;
  const int wv = t >> 6;           // wave id
  // accumulators: vlad 4k x 8c, plus per-k assignment sums
  float vacc[4][8];
  float asum[4] = {0.f, 0.f, 0.f, 0.f};
#pragma unroll
  for (int r = 0; r < 4; ++r)
#pragma unroll
    for (int c = 0; c < 8; ++c) vacc[r][c] = 0.f;

  __syncthreads();  // w_lds / b_lds ready

  for (int ch = 0; ch < PB / TT; ++ch) {
    const int p0 = p_base + ch * TT;
    // ---- stage x chunk, transposed to [p][c] ----
#pragma unroll
    for (int pass = 0; pass < 4; ++pass) {
      int c = (t >> 3) + (pass << 5);
      int q = t & 7;  // which float4 along p
      float4 v = *(const float4*)&x[(((size_t)n * CC + c) << 12) + p0 + (q << 2)];
      int p = q << 2;
      x_lds[(p + 0) * XS + c] = v.x;
      x_lds[(p + 1) * XS + c] = v.y;
      x_lds[(p + 2) * XS + c] = v.z;
      x_lds[(p + 3) * XS + c] = v.w;
    }
    __syncthreads();

    // ---- logits: k = k0..k0+3, p = tp and tp+16 ----
    float lg[4][2];
#pragma unroll
    for (int r = 0; r < 4; ++r) { lg[r][0] = b_lds[k0 + r]; lg[r][1] = lg[r][0]; }
#pragma unroll 8
    for (int c4 = 0; c4 < CC; c4 += 4) {
      float4 xa = *(const float4*)&x_lds[tp * XS + c4];
      float4 xb = *(const float4*)&x_lds[(tp + 16) * XS + c4];
#pragma unroll
      for (int r = 0; r < 4; ++r) {
        float4 w4 = *(const float4*)&w_lds[(k0 + r) * WSR + c4];
        lg[r][0] += w4.x * xa.x + w4.y * xa.y + w4.z * xa.z + w4.w * xa.w;
        lg[r][1] += w4.x * xb.x + w4.y * xb.y + w4.z * xb.z + w4.w * xb.w;
      }
    }
#pragma unroll
    for (int r = 0; r < 4; ++r) {
      a_lds[tp * AS + k0 + r] = lg[r][0];
      a_lds[(tp + 16) * AS + k0 + r] = lg[r][1];
    }
    __syncthreads();

    // ---- softmax over k (K=64 == wave width): one wave per row ----
    {
      const int ln = t & 63;
      for (int sp = wv; sp < TT; sp += 4) {
        float v = a_lds[sp * AS + ln];
        float m = v;
#pragma unroll
        for (int off = 32; off > 0; off >>= 1) m = fmaxf(m, __shfl_xor(m, off, 64));
        float e = __expf(v - m);
        float s = e;
#pragma unroll
        for (int off = 32; off > 0; off >>= 1) s += __shfl_xor(s, off, 64);
        a_lds[sp * AS + ln] = e * (1.0f / s);
      }
    }
    __syncthreads();

    // ---- vlad accumulate: vacc[r][c] += a[p][k0+r] * x[p][c0+c] ----
#pragma unroll 8
    for (int p = 0; p < TT; ++p) {
      float4 av = *(const float4*)&a_lds[p * AS + k0];
      float4 x0 = *(const float4*)&x_lds[p * XS + c0];
      float4 x1 = *(const float4*)&x_lds[p * XS + c0 + 4];
      float a4[4] = {av.x, av.y, av.z, av.w};
      float xv[8] = {x0.x, x0.y, x0.z, x0.w, x1.x, x1.y, x1.z, x1.w};
#pragma unroll
      for (int r = 0; r < 4; ++r) {
        asum[r] += a4[r];
#pragma unroll
        for (int c = 0; c < 8; ++c) vacc[r][c] += a4[r] * xv[c];
      }
    }
    __syncthreads();  // protect x_lds/a_lds before next chunk
  }

  // ---- write partials ----
  const size_t base = ((size_t)(n * BSPLIT + blk)) * (KK * CC);
#pragma unroll
  for (int r = 0; r < 4; ++r) {
    float4 v0 = make_float4(vacc[r][0], vacc[r][1], vacc[r][2], vacc[r][3]);
    float4 v1 = make_float4(vacc[r][4], vacc[r][5], vacc[r][6], vacc[r][7]);
    *(float4*)&vlad_part[base + (size_t)(k0 + r) * CC + c0] = v0;
    *(float4*)&vlad_part[base + (size_t)(k0 + r) * CC + c0 + 4] = v1;
  }
  if (tc == 0) {
    int ab = (n * BSPLIT + blk) * KK;
#pragma unroll
    for (int r = 0; r < 4; ++r) asum_part[ab + k0 + r] = asum[r];
  }
}

__global__ __launch_bounds__(256) void netvlad_reduce(
    const float* __restrict__ vlad_part, const float* __restrict__ asum_part,
    const float* __restrict__ centroids, float* __restrict__ out) {
  __shared__ float buf[KK * CC];  // 32 KB
  __shared__ float asum_l[KK];
  __shared__ float red[4];
  __shared__ float knorm[KK];
  __shared__ float gscale;
  const int t = threadIdx.x;
  const int n = blockIdx.x;

  if (t < KK) {
    float s = 0.f;
    for (int b = 0; b < BSPLIT; ++b) s += asum_part[(n * BSPLIT + b) * KK + t];
    asum_l[t] = s;
  }
  __syncthreads();

  for (int i = t; i < KK * CC; i += 256) {
    float s = 0.f;
#pragma unroll
    for (int b = 0; b < BSPLIT; ++b)
      s += vlad_part[((size_t)(n * BSPLIT + b)) * (KK * CC) + i];
    int k = i >> 7;
    buf[i] = s - asum_l[k] * centroids[i];  // i == k*128 + c
  }
  __syncthreads();

  // per-k L2 normalization scale
  const int wave = t >> 6, lane = t & 63;
  for (int k = wave; k < KK; k += 4) {
    float v0 = buf[(k << 7) + lane];
    float v1 = buf[(k << 7) + 64 + lane];
    float ss = v0 * v0 + v1 * v1;
#pragma unroll
    for (int off = 32; off > 0; off >>= 1) ss += __shfl_down(ss, off, 64);
    if (lane == 0) knorm[k] = 1.0f / fmaxf(sqrtf(ss), 1e-12f);
  }
  __syncthreads();

  // apply per-k scale, accumulate global sum of squares
  float acc = 0.f;
  for (int i = t; i < KK * CC; i += 256) {
    float v = buf[i] * knorm[i >> 7];
    buf[i] = v;
    acc += v * v;
  }
#pragma unroll
  for (int off = 32; off > 0; off >>= 1) acc += __shfl_down(acc, off, 64);
  if (lane == 0) red[wave] = acc;
  __syncthreads();
  if (t == 0) gscale = 1.0f / fmaxf(sqrtf(red[0] + red[1] + red[2] + red[3]), 1e-12f);
  __syncthreads();

  for (int i = t; i < KK * CC; i += 256)
    out[((size_t)n) * (KK * CC) + i] = buf[i] * gscale;
}

extern "C" void kernel_launch(void* const* d_in, const int* in_sizes, int n_in,
                              void* d_out, int out_size, void* d_ws, size_t ws_size,
                              hipStream_t stream) {
  const float* x = (const float*)d_in[0];          // (64,128,64,64)
  const float* conv_w = (const float*)d_in[1];     // (64,128)
  const float* conv_b = (const float*)d_in[2];     // (64,)
  const float* centroids = (const float*)d_in[3];  // (64,128)
  float* out = (float*)d_out;                      // (64, 8192)

  // workspace: vlad partials (N*BSPLIT*K*C fp32 = 16 MiB) + asum partials (128 KB)
  float* vlad_part = (float*)d_ws;
  float* asum_part = vlad_part + (size_t)NN * BSPLIT * KK * CC;

  netvlad_fused<<<NN * BSPLIT, 256, 0, stream>>>(x, conv_w, conv_b, vlad_part, asum_part);
  netvlad_reduce<<<NN, 256, 0, stream>>>(vlad_part, asum_part, centroids, out);
}

// Round 2
// 246.950 us; speedup vs baseline: 1.5910x; 1.5910x over previous
//
#include <hip/hip_runtime.h>
#include <math.h>

// NetVLAD, MFMA split-bf16. Sizes fixed: N=64, C=128, P=4096, K=64.
#define NNIMG 64
#define CCH 128
#define KK 64
#define PP 4096
#define BSPLIT 8
#define PB (PP / BSPLIT)   // 512 pixels per block
#define PC 64              // pixels per chunk
#define NCHUNK (PB / PC)   // 8

typedef __attribute__((ext_vector_type(8))) short short8;
typedef __attribute__((ext_vector_type(4))) float f32x4;

__device__ inline unsigned short bf16_hi(float f) {
  unsigned u = __float_as_uint(f);
  unsigned r = u + 0x7FFFu + ((u >> 16) & 1u);  // RTNE
  return (unsigned short)(r >> 16);
}
__device__ inline float bf16_tof(unsigned short h) {
  return __uint_as_float(((unsigned)h) << 16);
}

// LDS:
//  pc_hl : u32 [p=64][c stride 132]  (hi|lo<<16), c XOR-swizzled by 8*((p>>2)&3)  33792 B
//  cp_hi : u16 [c=128][p stride 72]                                              18432 B
//  a_lds : u16 [k=64][p stride 72]   assignments bf16                             9216 B
//  b_lds : f32[64], asum_buf f32[4][64]                                           1280 B
// total 62720 B -> 2 blocks/CU.
__global__ __launch_bounds__(256, 2) void netvlad_main(
    const float* __restrict__ x, const float* __restrict__ conv_w,
    const float* __restrict__ conv_b, float* __restrict__ vlad_part,
    float* __restrict__ asum_part) {
  __shared__ unsigned int pc_hl[PC * 132];
  __shared__ unsigned short cp_hi[CCH * 72];
  __shared__ unsigned short a_lds[KK * 72];
  __shared__ float b_lds[KK];
  __shared__ float asum_buf[4 * KK];

  const int t = threadIdx.x;
  const int lane = t & 63;
  const int w = t >> 6;       // wave 0..3
  const int m = lane & 15;    // 16-row/col id inside MFMA tile
  const int q = lane >> 4;    // quad

  const int n = blockIdx.x / BSPLIT;
  const int blk = blockIdx.x % BSPLIT;

  if (t < KK) b_lds[t] = conv_b[t];

  // ---- W fragments (hi + lo) in registers: A-operand layout A[m=lane&15][c=q*8+j]
  short8 Whi[4][4], Wlo[4][4];
#pragma unroll
  for (int kt = 0; kt < 4; ++kt) {
#pragma unroll
    for (int cs = 0; cs < 4; ++cs) {
      const float* wp = conv_w + (kt * 16 + m) * CCH + cs * 32 + q * 8;
      float4 wa = *(const float4*)wp;
      float4 wb = *(const float4*)(wp + 4);
      float fv[8] = {wa.x, wa.y, wa.z, wa.w, wb.x, wb.y, wb.z, wb.w};
      short8 h, l;
#pragma unroll
      for (int j = 0; j < 8; ++j) {
        unsigned short hb = bf16_hi(fv[j]);
        h[j] = (short)hb;
        l[j] = (short)bf16_hi(fv[j] - bf16_tof(hb));
      }
      Whi[kt][cs] = h;
      Wlo[kt][cs] = l;
    }
  }

  f32x4 vacc[4][2];  // V[k=64][c slice 32]: ktile x ctile
#pragma unroll
  for (int kt = 0; kt < 4; ++kt)
#pragma unroll
    for (int ct = 0; ct < 2; ++ct) vacc[kt][ct] = (f32x4){0.f, 0.f, 0.f, 0.f};
  float asum_acc[16];
#pragma unroll
  for (int i = 0; i < 16; ++i) asum_acc[i] = 0.f;

  const int crow = t >> 3;          // staging: c row 0..31 (+32*ci)
  const int pr = t & 7;             // staging: p quad id
  const int prow_w = w * 16 + m;    // GEMM1: this lane's p column (chunk-local)
  const int swz_r = 8 * ((prow_w >> 2) & 3);

#pragma unroll 1
  for (int ch = 0; ch < NCHUNK; ++ch) {
    __syncthreads();  // previous chunk's GEMM2 done; ch=0: b_lds ready
    // ---- stage x chunk: pc_hl [p][c] packed hi/lo, cp_hi [c][p] hi ----
    const float* xb = x + (size_t)n * CCH * PP + blk * PB + ch * PC;
#pragma unroll
    for (int ci = 0; ci < 4; ++ci) {
      int c = crow + ci * 32;
      const float* xr = xb + (size_t)c * PP;
#pragma unroll
      for (int rep = 0; rep < 2; ++rep) {
        int pl = pr * 4 + rep * 32;
        float4 v = *(const float4*)(xr + pl);
        float fv[4] = {v.x, v.y, v.z, v.w};
        unsigned short h[4], lo[4];
#pragma unroll
        for (int j = 0; j < 4; ++j) {
          h[j] = bf16_hi(fv[j]);
          lo[j] = bf16_hi(fv[j] - bf16_tof(h[j]));
        }
        uint2 cpv;
        cpv.x = (unsigned)h[0] | ((unsigned)h[1] << 16);
        cpv.y = (unsigned)h[2] | ((unsigned)h[3] << 16);
        *(uint2*)&cp_hi[c * 72 + pl] = cpv;
        int cc = c ^ (8 * ((pl >> 2) & 3));
#pragma unroll
        for (int j = 0; j < 4; ++j)
          pc_hl[(pl + j) * 132 + cc] = (unsigned)h[j] | ((unsigned)lo[j] << 16);
      }
    }
    __syncthreads();

    // ---- GEMM1: logits L[k=64][p: wave's 16 cols], 3-term split ----
    f32x4 acc1[4];
#pragma unroll
    for (int kt = 0; kt < 4; ++kt) acc1[kt] = (f32x4){0.f, 0.f, 0.f, 0.f};
    const unsigned int* pcrow = pc_hl + prow_w * 132;
#pragma unroll
    for (int cs = 0; cs < 4; ++cs) {
      int base = cs * 32 + ((q << 3) ^ swz_r);
      uint4 s0 = *(const uint4*)&pcrow[base];
      uint4 s1 = *(const uint4*)&pcrow[base + 4];
      unsigned int ss[8] = {s0.x, s0.y, s0.z, s0.w, s1.x, s1.y, s1.z, s1.w};
      unsigned int hs[4], ls[4];
#pragma unroll
      for (int i = 0; i < 4; ++i) {
        hs[i] = __builtin_amdgcn_perm(ss[2 * i + 1], ss[2 * i], 0x05040100u);
        ls[i] = __builtin_amdgcn_perm(ss[2 * i + 1], ss[2 * i], 0x07060302u);
      }
      short8 Bh, Bl;
      __builtin_memcpy(&Bh, hs, 16);
      __builtin_memcpy(&Bl, ls, 16);
#pragma unroll
      for (int kt = 0; kt < 4; ++kt) {
        acc1[kt] = __builtin_amdgcn_mfma_f32_16x16x32_bf16(Whi[kt][cs], Bh, acc1[kt], 0, 0, 0);
        acc1[kt] = __builtin_amdgcn_mfma_f32_16x16x32_bf16(Whi[kt][cs], Bl, acc1[kt], 0, 0, 0);
        acc1[kt] = __builtin_amdgcn_mfma_f32_16x16x32_bf16(Wlo[kt][cs], Bh, acc1[kt], 0, 0, 0);
      }
    }

    // ---- softmax over k (in registers; lane holds 16 of 64 k for its p col) ----
    float ssum = 0.f;
#pragma unroll
    for (int kt = 0; kt < 4; ++kt)
#pragma unroll
      for (int r = 0; r < 4; ++r) {
        float e = __expf(acc1[kt][r] + b_lds[kt * 16 + q * 4 + r]);
        acc1[kt][r] = e;
        ssum += e;
      }
    ssum += __shfl_xor(ssum, 16, 64);
    ssum += __shfl_xor(ssum, 32, 64);
    float inv = 1.0f / ssum;
#pragma unroll
    for (int kt = 0; kt < 4; ++kt)
#pragma unroll
      for (int r = 0; r < 4; ++r) {
        float a = acc1[kt][r] * inv;
        asum_acc[kt * 4 + r] += a;  // fp32-exact assignment sums
        a_lds[(kt * 16 + q * 4 + r) * 72 + prow_w] = bf16_hi(a);
      }
    __syncthreads();

    // ---- GEMM2: V[k][c] += A[k][p] * X^T[p][c] (hi-only X) ----
#pragma unroll
    for (int ps = 0; ps < 2; ++ps) {
      short8 Af[4];
#pragma unroll
      for (int kt = 0; kt < 4; ++kt)
        Af[kt] = *(const short8*)&a_lds[(kt * 16 + m) * 72 + ps * 32 + q * 8];
#pragma unroll
      for (int ct = 0; ct < 2; ++ct) {
        short8 Bf = *(const short8*)&cp_hi[(w * 32 + ct * 16 + m) * 72 + ps * 32 + q * 8];
#pragma unroll
        for (int kt = 0; kt < 4; ++kt)
          vacc[kt][ct] = __builtin_amdgcn_mfma_f32_16x16x32_bf16(Af[kt], Bf, vacc[kt][ct], 0, 0, 0);
      }
    }
  }

  // ---- epilogue: write V partials + per-block asum ----
  const size_t vbase = (size_t)blockIdx.x * (KK * CCH);
#pragma unroll
  for (int kt = 0; kt < 4; ++kt)
#pragma unroll
    for (int ct = 0; ct < 2; ++ct)
#pragma unroll
      for (int r = 0; r < 4; ++r)
        vlad_part[vbase + (kt * 16 + q * 4 + r) * CCH + (w * 32 + ct * 16 + m)] =
            vacc[kt][ct][r];
#pragma unroll
  for (int i = 0; i < 16; ++i) {
    float v = asum_acc[i];
    v += __shfl_xor(v, 1, 64);
    v += __shfl_xor(v, 2, 64);
    v += __shfl_xor(v, 4, 64);
    v += __shfl_xor(v, 8, 64);
    if (m == 0) asum_buf[w * 64 + (i >> 2) * 16 + q * 4 + (i & 3)] = v;
  }
  __syncthreads();
  if (t < 64) {
    float s = asum_buf[t] + asum_buf[64 + t] + asum_buf[128 + t] + asum_buf[192 + t];
    asum_part[blockIdx.x * 64 + t] = s;
  }
}

// One wave per (n,k): sum 8 partials, subtract asum*centroid, per-cluster L2 norm.
// Global norm over the per-cluster-normalized vector is exactly sqrt(64) -> x0.125.
__global__ __launch_bounds__(256) void netvlad_finish(
    const float* __restrict__ vlad_part, const float* __restrict__ asum_part,
    const float* __restrict__ centroids, float* __restrict__ out) {
  const int t = threadIdx.x;
  const int w = t >> 6, ln = t & 63;
  const int idx = blockIdx.x * 4 + w;  // 0..4095
  const int n = idx >> 6, k = idx & 63;
  const int c = ln * 2;
  float v0 = 0.f, v1 = 0.f;
#pragma unroll
  for (int b = 0; b < BSPLIT; ++b) {
    float2 pv = *(const float2*)&vlad_part[(size_t)(n * BSPLIT + b) * (KK * CCH) + k * CCH + c];
    v0 += pv.x;
    v1 += pv.y;
  }
  float s = 0.f;
#pragma unroll
  for (int b = 0; b < BSPLIT; ++b) s += asum_part[(n * BSPLIT + b) * KK + k];
  float2 ce = *(const float2*)&centroids[k * CCH + c];
  v0 -= s * ce.x;
  v1 -= s * ce.y;
  float ssq = v0 * v0 + v1 * v1;
#pragma unroll
  for (int off = 32; off > 0; off >>= 1) ssq += __shfl_xor(ssq, off, 64);
  float inv = 0.125f / fmaxf(sqrtf(ssq), 1e-12f);
  float2 o;
  o.x = v0 * inv;
  o.y = v1 * inv;
  *(float2*)&out[(size_t)n * (KK * CCH) + k * CCH + c] = o;
}

extern "C" void kernel_launch(void* const* d_in, const int* in_sizes, int n_in,
                              void* d_out, int out_size, void* d_ws, size_t ws_size,
                              hipStream_t stream) {
  const float* x = (const float*)d_in[0];          // (64,128,64,64)
  const float* conv_w = (const float*)d_in[1];     // (64,128)
  const float* conv_b = (const float*)d_in[2];     // (64,)
  const float* centroids = (const float*)d_in[3];  // (64,128)
  float* out = (float*)d_out;                      // (64, 8192)

  float* vlad_part = (float*)d_ws;                               // 16 MiB
  float* asum_part = vlad_part + (size_t)NNIMG * BSPLIT * KK * CCH;  // 128 KiB

  netvlad_main<<<NNIMG * BSPLIT, 256, 0, stream>>>(x, conv_w, conv_b, vlad_part, asum_part);
  netvlad_finish<<<NNIMG * KK / 4, 256, 0, stream>>>(vlad_part, asum_part, centroids, out);
}